// Round 7
// baseline (1134.976 us; speedup 1.0000x reference)
//
#include <hip/hip_runtime.h>

#define N_NODES 50000
#define MPAD    50176   // 196*256 = 98*512 = 784*64
#define DIM     1024
#define HEAD    16
#define KV      128
#define HD      64
#define NGRP    98      // MPAD/512
#define NTILE   784     // MPAD/64

typedef unsigned short ushort_t;
typedef short short8 __attribute__((ext_vector_type(8)));
typedef float f32x4 __attribute__((ext_vector_type(4)));

__device__ inline unsigned short f2bf(float f){
  union { float f; unsigned u; } v; v.f = f;
  unsigned u = v.u;
  unsigned r = (u + 0x7FFFu + ((u >> 16) & 1u)) >> 16;
  return (unsigned short)r;
}
__device__ inline float bf2f(unsigned u16){
  union { unsigned u; float f; } v; v.u = (u16 & 0xFFFFu) << 16; return v.f;
}

__device__ inline void gload_lds16(const void* g, void* l){
  __builtin_amdgcn_global_load_lds(
      (const __attribute__((address_space(1))) void*)g,
      (__attribute__((address_space(3))) void*)l, 16, 0, 0);
}

// [*][64] / [*][128] bf16 LDS tiles, 16B-chunk XOR-swizzled by (row&7)  (attn kernels)
__device__ inline short8 frag64(const ushort_t* lds, int row, int kk, int lane){
  int c  = kk*4 + (lane >> 4);
  int cc = c ^ (row & 7);
  return *(const short8*)(lds + row*64 + cc*8);
}
__device__ inline short8 frag128(const ushort_t* lds, int row, int kk, int lane){
  int c  = kk*4 + (lane >> 4);
  int cc = c ^ (row & 7);
  return *(const short8*)(lds + row*128 + cc*8);
}

// ---------------- prep kernels ----------------
__global__ void k_zero(float* p, int n){
  int i = blockIdx.x*256 + threadIdx.x;
  if (i < n) p[i] = 0.f;
}

// x fp32 -> bf16, GEMM layout: within each row, chunk c -> (c&~3)|((c^(row>>1))&3)
__global__ void k_prep_x(const float* __restrict__ x, ushort_t* __restrict__ x_bf){
  int idx = blockIdx.x*256 + threadIdx.x;
  int row = idx >> 7, c = idx & 127;
  const float4* s = (const float4*)(x + (size_t)row*1024 + c*8);
  float4 f0 = s[0], f1 = s[1];
  short8 v;
  v[0]=(short)f2bf(f0.x); v[1]=(short)f2bf(f0.y); v[2]=(short)f2bf(f0.z); v[3]=(short)f2bf(f0.w);
  v[4]=(short)f2bf(f1.x); v[5]=(short)f2bf(f1.y); v[6]=(short)f2bf(f1.z); v[7]=(short)f2bf(f1.w);
  int sc = (c & ~3) | ((c ^ (row >> 1)) & 3);
  *(short8*)(x_bf + (size_t)row*1024 + sc*8) = v;
}

// W concat, bf16, same GEMM chunk layout
__global__ void k_prep_w(const float* __restrict__ Wq, const float* __restrict__ Wv,
                         ushort_t* __restrict__ w_bf){
  int idx = blockIdx.x*256 + threadIdx.x;
  int j = idx >> 10, k = idx & 1023;
  float v = (j < 1024) ? Wq[idx] : Wv[(size_t)(j-1024)*1024 + k];
  int l = k >> 3;
  int q = (l & ~3) | ((l ^ (j >> 1)) & 3);
  w_bf[(size_t)j*1024 + q*8 + (k & 7)] = f2bf(v);
}

// key_bf[h][r][swz(d, r)]  from key_p[r][h][d]
__global__ void k_prep_key(const float* __restrict__ key_p, ushort_t* __restrict__ key_bf){
  int idx = blockIdx.x*256 + threadIdx.x;
  int h = idx >> 13, rem = idx & 8191;
  int r = rem >> 6, d = rem & 63;
  float v = key_p[(size_t)(r*HEAD + h)*HD + d];
  int pos = ((((d>>3) ^ (r & 7)) & 7) << 3) | (d & 7);
  key_bf[(size_t)h*8192 + r*64 + pos] = f2bf(v);
}

// sum the NGRP v-slices
__global__ void k_vreduce(const float* __restrict__ vp, float* __restrict__ vout){
  int i = blockIdx.x*256 + threadIdx.x;
  float s = 0.f;
  for (int gg = 0; gg < NGRP; ++gg) s += vp[(size_t)gg*131072 + i];
  vout[i] = s;
}

// ---------------- big GEMM (unchanged from r6) ----------------
__global__ __launch_bounds__(512) void k_gemm(const ushort_t* __restrict__ x_bf,
    const ushort_t* __restrict__ w_bf, const float* __restrict__ bq,
    const float* __restrict__ bv, ushort_t* __restrict__ q_bf, float* xv_out){
  extern __shared__ char gsm[];
  ushort_t* lds = (ushort_t*)gsm;
  const int tid = threadIdx.x, lane = tid & 63;
  const int wid = tid >> 6, wr = wid >> 2, wc = wid & 3;
  int b = blockIdx.x;
  int wg = (b & 7)*196 + (b >> 3);
  const int bm0 = (wg >> 3) * 256, bn0 = (wg & 7) * 256;
  const int pA = (lane >> 4) ^ ((lane >> 1) & 3);

  f32x4 acc[8][4];
  #pragma unroll
  for (int m=0;m<8;m++)
    #pragma unroll
    for (int n=0;n<4;n++) acc[m][n] = (f32x4){0.f,0.f,0.f,0.f};

  const ushort_t* asrc = x_bf + (size_t)bm0*1024;
  const ushort_t* bsrc = w_bf + (size_t)bn0*1024;

#define STG(kt, kk, bi) do{                                               \
    _Pragma("unroll")                                                     \
    for (int it=0; it<2; ++it){                                           \
      int ch = it*512 + tid; int r = ch>>2, c = ch&3;                     \
      gload_lds16(asrc + (size_t)r*1024 + (kt)*64 + (kk)*32 + c*8,        \
                  lds + (bi)*32768 + (kk)*8192 + ch*8);                   \
      gload_lds16(bsrc + (size_t)r*1024 + (kt)*64 + (kk)*32 + c*8,        \
                  lds + (bi)*32768 + 16384 + (kk)*8192 + ch*8);           \
    } }while(0)

#define RD_A(BASE, KK, MH)                                                \
    _Pragma("unroll")                                                     \
    for (int m=0;m<4;m++){                                                \
      int row = wr*128 + ((MH)*4+m)*16 + (lane&15);                       \
      af[m] = *(const short8*)((BASE) + (KK)*8192 + row*32 + pA*8);       \
    }
#define RD_B(BASE, KK)                                                    \
    _Pragma("unroll")                                                     \
    for (int n=0;n<4;n++){                                                \
      int row = wc*64 + n*16 + (lane&15);                                 \
      bf_[n] = *(const short8*)((BASE) + 16384 + (KK)*8192 + row*32 + pA*8); \
    }
#define MFMA16(MH)                                                        \
    __builtin_amdgcn_s_setprio(1);                                        \
    _Pragma("unroll")                                                     \
    for (int m=0;m<4;m++)                                                 \
      _Pragma("unroll")                                                   \
      for (int n=0;n<4;n++)                                               \
        acc[(MH)*4+m][n] = __builtin_amdgcn_mfma_f32_16x16x32_bf16(       \
            af[m], bf_[n], acc[(MH)*4+m][n], 0,0,0);                      \
    __builtin_amdgcn_s_setprio(0);
#define BAR asm volatile("s_barrier" ::: "memory")

  STG(0,0,0); STG(0,1,0); STG(1,0,1);
  asm volatile("s_waitcnt vmcnt(8)" ::: "memory");
  BAR;

  for (int t = 0; t < 16; ++t){
    const int bufc = t & 1, bufn = bufc ^ 1;
    const ushort_t* base = lds + bufc*32768;
    short8 af[4], bf_[4];

    RD_B(base, 0);
    RD_A(base, 0, 0);
    if (t+1 < 16) STG(t+1, 1, bufn);
    BAR;
    MFMA16(0);
    BAR;

    RD_A(base, 0, 1);
    BAR;
    MFMA16(1);
    if (t == 15) { asm volatile("s_waitcnt vmcnt(0)" ::: "memory"); }
    else         { asm volatile("s_waitcnt vmcnt(8)" ::: "memory"); }
    BAR;

    RD_B(base, 1);
    RD_A(base, 1, 0);
    if (t+2 < 16) STG(t+2, 0, bufc);
    BAR;
    MFMA16(0);
    BAR;

    RD_A(base, 1, 1);
    BAR;
    MFMA16(1);
    if (t <= 13)      { asm volatile("s_waitcnt vmcnt(8)" ::: "memory"); }
    else if (t == 14) { asm volatile("s_waitcnt vmcnt(4)" ::: "memory"); }
    BAR;
  }
#undef STG
#undef RD_A
#undef RD_B
#undef MFMA16
#undef BAR

  __syncthreads();

  const bool isq = bn0 < 1024;
  float biasv[4];
  #pragma unroll
  for (int n=0;n<4;n++){
    int col = bn0 + wc*64 + n*16 + (lane & 15);
    biasv[n] = isq ? bq[col] : bv[col - 1024];
  }

  if (isq){
    ushort_t* img = (ushort_t*)gsm;
    #pragma unroll
    for (int n=0;n<4;n++){
      int lcol = wc*64 + n*16 + (lane & 15);
      int d = lcol & 63;
      #pragma unroll
      for (int m=0;m<8;m++){
        #pragma unroll
        for (int j=0;j<4;j++){
          int lrow = wr*128 + m*16 + (lane>>4)*4 + j;
          int sc = (lcol & ~63) | ((((d>>3) ^ (lrow & 7)) & 7) << 3) | (d & 7);
          img[lrow*256 + sc] = f2bf(acc[m][n][j] + biasv[n]);
        }
      }
    }
    __syncthreads();
    #pragma unroll
    for (int it=0; it<16; ++it){
      int r  = it*16 + (tid >> 5);
      int ch = tid & 31;
      short8 v = *(const short8*)(img + r*256 + ch*8);
      *(short8*)(q_bf + (size_t)(bm0 + r)*1024 + bn0 + ch*8) = v;
    }
  } else {
    #pragma unroll
    for (int n=0;n<4;n++){
      int col = bn0 + wc*64 + n*16 + (lane & 15);
      #pragma unroll
      for (int m=0;m<8;m++){
        #pragma unroll
        for (int j=0;j<4;j++){
          int row = bm0 + wr*128 + m*16 + (lane>>4)*4 + j;
          if (row < N_NODES)
            xv_out[(size_t)row*1024 + (col - 1024)] = acc[m][n][j] + biasv[n];
        }
      }
    }
  }
}

// ---------------- attn passes (P0 producer + legacy P1/P2 fallback) ----------------
template<int PHASE>
__global__ __launch_bounds__(256) void k_attn(
    const ushort_t* __restrict__ q_bf, const ushort_t* __restrict__ key_bf,
    const float* __restrict__ node_index, const float* __restrict__ Wb,
    const float* __restrict__ bb, const float* __restrict__ colsum_in,
    float* __restrict__ colsum_out, const float* __restrict__ v_fin,
    float* __restrict__ v_part, float* xv_out,
    const float* __restrict__ alpha, const float* __restrict__ beta,
    ushort_t* __restrict__ q0g)
{
  constexpr int QB    = (PHASE == 2) ? 1 : 2;
  constexpr int O_Q   = 0;
  constexpr int O_KEY = O_Q + QB*8192;
  constexpr int O_NI  = O_KEY + 16384;
  constexpr int O_WB  = O_NI + QB*1024;
  constexpr int O_RED = O_WB + 2560;
  constexpr int O_COL = O_RED + 2048;
  constexpr int O_W   = O_COL + 512;
  constexpr int O_X1  = O_W + 512;
  constexpr int O_X2  = O_X1 + 16384;

  extern __shared__ char smem[];
  ushort_t* q_lds   = (ushort_t*)(smem + O_Q);
  ushort_t* key_lds = (ushort_t*)(smem + O_KEY);
  float* ni_lds  = (float*)(smem + O_NI);
  float* wb_lds  = (float*)(smem + O_WB);
  float* red_lds = (float*)(smem + O_RED);
  float* col_acc = (float*)(smem + O_COL);
  float* w_lds   = (float*)(smem + O_W);
  ushort_t* sigT     = (ushort_t*)(smem + O_X1);
  ushort_t* xvT      = (ushort_t*)(smem + O_X2);
  ushort_t* vT       = (ushort_t*)(smem + O_X1);
  ushort_t* cons_lds = (ushort_t*)(smem + O_X2);
  float*    out_lds  = (float*)(smem + O_X2);

  const int tid = threadIdx.x, lane = tid & 63, wid = tid >> 6;
  const int h    = blockIdx.x & 15;
  const int g    = blockIdx.x >> 4;
  const int base = g * 512;
  int NT = (MPAD - base) >> 6; if (NT > 8) NT = 8;

  #pragma unroll
  for (int it = 0; it < 4; ++it){
    int chunk = it*256 + tid;
    gload_lds16(key_bf + (size_t)h*8192 + chunk*8, key_lds + chunk*8);
  }
  #pragma unroll
  for (int it = 0; it < 2; ++it){
    int chunk = it*256 + tid;
    int r = chunk >> 3, c = chunk & 7;
    gload_lds16(q_bf + (size_t)(base + r)*1024 + h*64 + c*8, q_lds + chunk*8);
  }
  { int r = tid >> 2, c = tid & 3;
    ni_lds[tid] = (base + r < N_NODES) ? node_index[(size_t)(base + r)*4 + c] : 0.f; }
  if (tid < 128){
    #pragma unroll
    for (int c=0;c<4;c++) wb_lds[tid*5+c] = Wb[(size_t)(h*128 + tid)*4 + c];
    wb_lds[tid*5+4] = bb[h*128 + tid];
    if (PHASE >= 1) w_lds[tid] = 1.f / (128.f * colsum_in[h*128 + tid]);
    if (PHASE <= 1) col_acc[tid] = 0.f;
  }
  if constexpr (PHASE == 2){
    int r = tid >> 1, dh = (tid & 1)*32;
    #pragma unroll
    for (int i=0;i<32;i++){
      int d = dh + i;
      vT[d*128 + ((r>>3) ^ (d&7))*8 + (r&7)] = f2bf(v_fin[((size_t)r*16 + h)*64 + d]);
    }
  }
  float xvr[16], xvn[16];
  if constexpr (PHASE == 0){
    int d = tid & 63, q4 = tid >> 6;
    #pragma unroll
    for (int i=0;i<16;i++){
      int row = base + q4*16 + i;
      xvr[i] = (row < N_NODES) ? xv_out[(size_t)row*1024 + h*64 + d] : 0.f;
    }
  }
  f32x4 vac[2][4];
  if constexpr (PHASE == 0)
    for (int m=0;m<2;m++) for (int n=0;n<4;n++) vac[m][n] = (f32x4){0.f,0.f,0.f,0.f};

  __syncthreads();

  for (int t = 0; t < NT; ++t){
    const int i0  = base + t*64;
    const int cur = t & 1;
    const ushort_t* qb  = q_lds  + ((QB==2) ? cur*4096 : 0);
    const float*    nib = ni_lds + ((QB==2) ? cur*256  : 0);
    float ni_next = 0.f;

    if constexpr (QB == 2){
      if (t+1 < NT){
        int i1 = i0 + 64;
        #pragma unroll
        for (int it = 0; it < 2; ++it){
          int chunk = it*256 + tid;
          int r = chunk >> 3, c = chunk & 7;
          gload_lds16(q_bf + (size_t)(i1 + r)*1024 + h*64 + c*8,
                      q_lds + (cur^1)*4096 + chunk*8);
        }
        int r = tid >> 2, c = tid & 3;
        ni_next = (i0 + 64 + r < N_NODES) ? node_index[(size_t)(i0+64+r)*4 + c] : 0.f;
      }
    } else {
      if (t+1 < NT){
        int r = tid >> 2, c = tid & 3;
        ni_next = (i0 + 64 + r < N_NODES) ? node_index[(size_t)(i0+64+r)*4 + c] : 0.f;
      }
    }
    if constexpr (PHASE == 0){
      if (t+1 < NT){
        int d = tid & 63, q4 = tid >> 6;
        #pragma unroll
        for (int i=0;i<16;i++){
          int row = i0 + 64 + q4*16 + i;
          xvn[i] = (row < N_NODES) ? xv_out[(size_t)row*1024 + h*64 + d] : 0.f;
        }
      }
    }

    f32x4 acc[2][4];
    for (int m=0;m<2;m++) for (int n=0;n<4;n++) acc[m][n] = (f32x4){0.f,0.f,0.f,0.f};
    #pragma unroll
    for (int kk = 0; kk < 2; ++kk){
      short8 kf[2];
      #pragma unroll
      for (int m=0;m<2;m++) kf[m] = frag64(key_lds, wid*32 + m*16 + (lane&15), kk, lane);
      #pragma unroll
      for (int n=0;n<4;n++){
        short8 qf = frag64(qb, n*16 + (lane&15), kk, lane);
        #pragma unroll
        for (int m=0;m<2;m++)
          acc[m][n] = __builtin_amdgcn_mfma_f32_16x16x32_bf16(kf[m], qf, acc[m][n], 0,0,0);
      }
    }

    float nif[4][4];
    #pragma unroll
    for (int n=0;n<4;n++){
      int nn = n*16 + (lane&15);
      #pragma unroll
      for (int c=0;c<4;c++) nif[n][c] = nib[nn*4+c];
    }
    float a[2][4][4];
    #pragma unroll
    for (int m=0;m<2;m++){
      #pragma unroll
      for (int j=0;j<4;j++){
        int r = wid*32 + m*16 + (lane>>4)*4 + j;
        float w0 = wb_lds[r*5+0], w1 = wb_lds[r*5+1];
        float w2 = wb_lds[r*5+2], w3 = wb_lds[r*5+3], w4 = wb_lds[r*5+4];
        #pragma unroll
        for (int n=0;n<4;n++){
          float b = w4 + w0*nif[n][0] + w1*nif[n][1] + w2*nif[n][2] + w3*nif[n][3];
          a[m][n][j] = acc[m][n][j]*0.125f + b;
        }
      }
    }

    float vmask[4];
    #pragma unroll
    for (int n=0;n<4;n++) vmask[n] = (i0 + n*16 + (lane&15) < N_NODES) ? 1.f : 0.f;

    if constexpr (PHASE == 0){
      #pragma unroll
      for (int m=0;m<2;m++) for (int n=0;n<4;n++) for (int j=0;j<4;j++){
        int r  = wid*32 + m*16 + (lane>>4)*4 + j;
        int nn = n*16 + (lane&15);
        float sg = vmask[n] / (1.f + __expf(-a[m][n][j]));
        sigT[r*64 + ((((nn>>3) ^ (r&7)) & 7) << 3) + (nn&7)] = f2bf(sg);
      }
      { int d = tid & 63, q4 = tid >> 6;
        #pragma unroll
        for (int i=0;i<16;i++){
          int nn = q4*16 + i;
          xvT[d*64 + ((((nn>>3) ^ (d&7)) & 7) << 3) + (nn&7)] = f2bf(xvr[i]);
        }
      }
    }

    float pm[4];
    #pragma unroll
    for (int n=0;n<4;n++){
      float m0 = a[0][n][0];
      #pragma unroll
      for (int m=0;m<2;m++) for (int j=0;j<4;j++) m0 = fmaxf(m0, a[m][n][j]);
      m0 = fmaxf(m0, __shfl_xor(m0, 16));
      m0 = fmaxf(m0, __shfl_xor(m0, 32));
      pm[n] = m0;
    }
    if (lane < 16){
      #pragma unroll
      for (int n=0;n<4;n++) red_lds[wid*64 + n*16 + lane] = pm[n];
    }
    __syncthreads();

    if constexpr (QB == 1){
      if (t+1 < NT){
        int i1 = i0 + 64;
        #pragma unroll
        for (int it = 0; it < 2; ++it){
          int chunk = it*256 + tid;
          int r = chunk >> 3, c = chunk & 7;
          gload_lds16(q_bf + (size_t)(i1 + r)*1024 + h*64 + c*8, q_lds + chunk*8);
        }
        ni_lds[tid] = ni_next;
      }
    }

    float mnn[4], snn[4];
    #pragma unroll
    for (int n=0;n<4;n++){
      int nn = n*16 + (lane&15);
      float m0 = red_lds[nn];
      m0 = fmaxf(m0, red_lds[64+nn]); m0 = fmaxf(m0, red_lds[128+nn]); m0 = fmaxf(m0, red_lds[192+nn]);
      mnn[n] = m0;
    }
    #pragma unroll
    for (int n=0;n<4;n++){
      float s = 0.f;
      #pragma unroll
      for (int m=0;m<2;m++) for (int j=0;j<4;j++){
        float e = __expf(a[m][n][j] - mnn[n]);
        a[m][n][j] = e; s += e;
      }
      s += __shfl_xor(s, 16); s += __shfl_xor(s, 32);
      snn[n] = s;
    }
    if (lane < 16){
      #pragma unroll
      for (int n=0;n<4;n++) red_lds[256 + wid*64 + n*16 + lane] = snn[n];
    }

    if constexpr (PHASE == 0){
      #pragma unroll
      for (int kk=0;kk<2;kk++){
        short8 sa[2];
        #pragma unroll
        for (int m=0;m<2;m++) sa[m] = frag64(sigT, wid*32 + m*16 + (lane&15), kk, lane);
        #pragma unroll
        for (int n=0;n<4;n++){
          short8 xf = frag64(xvT, n*16 + (lane&15), kk, lane);
          #pragma unroll
          for (int m=0;m<2;m++)
            vac[m][n] = __builtin_amdgcn_mfma_f32_16x16x32_bf16(sa[m], xf, vac[m][n], 0,0,0);
        }
      }
    }
    __syncthreads();

    #pragma unroll
    for (int n=0;n<4;n++){
      int nn = n*16 + (lane&15);
      snn[n] = red_lds[256+nn] + red_lds[256+64+nn] + red_lds[256+128+nn] + red_lds[256+192+nn];
    }
    #pragma unroll
    for (int n=0;n<4;n++){
      float inv = 20.f / snn[n];
      #pragma unroll
      for (int m=0;m<2;m++) for (int j=0;j<4;j++)
        a[m][n][j] = __expf(a[m][n][j] * inv);
    }

    // Q0 frag-layout store (coalesced 8B per thread per fragment)
    if constexpr (PHASE == 0){
      if (q0g){
        size_t ub = (size_t)((i0 >> 6)*16 + h) * 8192;
        #pragma unroll
        for (int m=0;m<2;m++) for (int n=0;n<4;n++){
          uint2 pv;
          pv.x = (unsigned)f2bf(a[m][n][0]) | ((unsigned)f2bf(a[m][n][1]) << 16);
          pv.y = (unsigned)f2bf(a[m][n][2]) | ((unsigned)f2bf(a[m][n][3]) << 16);
          *(uint2*)(q0g + ub + ((size_t)((wid*2+m)*4 + n))*256 + lane*4) = pv;
        }
      }
    }

    float uval[4];
    if constexpr (PHASE >= 1){
      #pragma unroll
      for (int n=0;n<4;n++){
        float s = 0.f;
        #pragma unroll
        for (int m=0;m<2;m++){
          #pragma unroll
          for (int j=0;j<4;j++){
            int r = wid*32 + m*16 + (lane>>4)*4 + j;
            s += a[m][n][j] * w_lds[r];
          }
        }
        s += __shfl_xor(s, 16); s += __shfl_xor(s, 32);
        uval[n] = s;
      }
      if (lane < 16){
        #pragma unroll
        for (int n=0;n<4;n++) red_lds[wid*64 + n*16 + lane] = uval[n];
      }
      __syncthreads();
      #pragma unroll
      for (int n=0;n<4;n++){
        int nn = n*16 + (lane&15);
        float s = red_lds[nn] + red_lds[64+nn] + red_lds[128+nn] + red_lds[192+nn];
        uval[n] = 1.f / (50000.f * s);
      }
    }

    if constexpr (PHASE <= 1){
      float cs[2][4];
      #pragma unroll
      for (int m=0;m<2;m++){
        #pragma unroll
        for (int j=0;j<4;j++){
          float s = 0.f;
          #pragma unroll
          for (int n=0;n<4;n++){
            float tv = a[m][n][j] * vmask[n];
            if (PHASE == 1) tv *= uval[n];
            s += tv;
          }
          s += __shfl_xor(s, 1); s += __shfl_xor(s, 2);
          s += __shfl_xor(s, 4); s += __shfl_xor(s, 8);
          cs[m][j] = s;
        }
      }
      if ((lane & 15) == 0){
        #pragma unroll
        for (int m=0;m<2;m++) for (int j=0;j<4;j++){
          int r = wid*32 + m*16 + (lane>>4)*4 + j;
          col_acc[r] += cs[m][j];
        }
      }
    }

    if constexpr (PHASE == 2){
      #pragma unroll
      for (int m=0;m<2;m++) for (int n=0;n<4;n++) for (int j=0;j<4;j++){
        int r  = wid*32 + m*16 + (lane>>4)*4 + j;
        int nn = n*16 + (lane&15);
        float cv = 50000.f * uval[n] * a[m][n][j] * w_lds[r];
        cons_lds[nn*128 + ((r>>3) ^ (nn&7))*8 + (r&7)] = f2bf(cv);
      }
      __syncthreads();
      f32x4 oac[4];
      for (int n=0;n<4;n++) oac[n] = (f32x4){0.f,0.f,0.f,0.f};
      #pragma unroll
      for (int kk=0;kk<4;kk++){
        short8 va = frag128(vT, wid*16 + (lane&15), kk, lane);
        #pragma unroll
        for (int n=0;n<4;n++){
          short8 cf = frag128(cons_lds, n*16 + (lane&15), kk, lane);
          oac[n] = __builtin_amdgcn_mfma_f32_16x16x32_bf16(va, cf, oac[n], 0,0,0);
        }
      }
      __syncthreads();
      #pragma unroll
      for (int n=0;n<4;n++) for (int j=0;j<4;j++){
        int d  = wid*16 + (lane>>4)*4 + j;
        int nn = n*16 + (lane&15);
        out_lds[nn*68 + d] = oac[n][j];
      }
      __syncthreads();
      float sa = 1.f/(1.f + __expf(-alpha[h]));
      float sb = 1.f/(1.f + __expf(-beta[h]));
      int nn = tid >> 2, d0 = (tid & 3)*16;
      if (i0 + nn < N_NODES){
        #pragma unroll
        for (int gq=0; gq<4; ++gq){
          float4 vf = *(const float4*)(out_lds + nn*68 + d0 + gq*4);
          float4 xf = *(const float4*)(xv_out + (size_t)(i0+nn)*1024 + h*64 + d0 + gq*4);
          float4 o;
          o.x = sa*xf.x + sb*vf.x;
          o.y = sa*xf.y + sb*vf.y;
          o.z = sa*xf.z + sb*vf.z;
          o.w = sa*xf.w + sb*vf.w;
          *(float4*)(xv_out + (size_t)(i0+nn)*1024 + h*64 + d0 + gq*4) = o;
        }
      }
    } else {
      if (t+1 < NT && QB == 2) ni_lds[(cur^1)*256 + tid] = ni_next;
      if constexpr (PHASE == 0){
        if (t+1 < NT){
          #pragma unroll
          for (int i=0;i<16;i++) xvr[i] = xvn[i];
        }
      }
      __syncthreads();
    }
  }

  if constexpr (PHASE == 0){
    float* vdst = v_part + (size_t)g*131072;
    #pragma unroll
    for (int m=0;m<2;m++) for (int n=0;n<4;n++) for (int j=0;j<4;j++){
      int r = wid*32 + m*16 + (lane>>4)*4 + j;
      int d = n*16 + (lane&15);
      vdst[((size_t)r*16 + h)*64 + d] = vac[m][n][j];
    }
  }
  if constexpr (PHASE <= 1){
    if (tid < 128) atomicAdd(&colsum_out[h*128 + tid], col_acc[tid]);
  }
}

// ---------------- streaming sinkhorn pass over materialized Q0 ----------------
// colsum_out[h,r] += sum_n u(n,h)*Q0 ; u = 1/(50000*sum_r Q0*w) ; w = 1/(128*cs_in)
__global__ __launch_bounds__(256) void k_p1(const ushort_t* __restrict__ q0g,
    const float* __restrict__ cs_in, float* __restrict__ cs_out){
  const int tid = threadIdx.x, lane = tid & 63, wid = tid >> 6;
  const int gw = blockIdx.x*4 + wid;     // 0..3135
  const int rg = lane >> 4, ln = lane & 15;
  #pragma unroll 1
  for (int it = 0; it < 4; ++it){
    int unit = gw*4 + it;                // 0..12543 = T*16 + h
    int T = unit >> 4, h = unit & 15;
    const ushort_t* ubase = q0g + (size_t)unit*8192;
    float wv[8][4];
    #pragma unroll
    for (int a2=0;a2<8;a2++){
      float4 c4 = *(const float4*)(cs_in + h*128 + a2*16 + rg*4);
      wv[a2][0] = 1.f/(128.f*c4.x); wv[a2][1] = 1.f/(128.f*c4.y);
      wv[a2][2] = 1.f/(128.f*c4.z); wv[a2][3] = 1.f/(128.f*c4.w);
    }
    float up[4] = {0.f,0.f,0.f,0.f};
    #pragma unroll
    for (int f=0; f<32; f++){
      uint2 d = *(const uint2*)(ubase + (size_t)f*256 + lane*4);
      int a2 = f>>2, n = f&3;
      up[n] += bf2f(d.x)*wv[a2][0] + bf2f(d.x>>16)*wv[a2][1]
             + bf2f(d.y)*wv[a2][2] + bf2f(d.y>>16)*wv[a2][3];
    }
    float msk[4];
    #pragma unroll
    for (int n=0;n<4;n++){
      float s = up[n];
      s += __shfl_xor(s,16); s += __shfl_xor(s,32);
      float uu = 1.f/(50000.f*s);
      msk[n] = (T*64 + n*16 + ln < N_NODES) ? uu : 0.f;
    }
    float ca[32];
    #pragma unroll
    for (int s5=0;s5<32;s5++) ca[s5] = 0.f;
    #pragma unroll
    for (int f=0; f<32; f++){
      uint2 d = *(const uint2*)(ubase + (size_t)f*256 + lane*4);
      int a2 = f>>2, n = f&3;
      ca[a2*4+0] += msk[n]*bf2f(d.x);
      ca[a2*4+1] += msk[n]*bf2f(d.x>>16);
      ca[a2*4+2] += msk[n]*bf2f(d.y);
      ca[a2*4+3] += msk[n]*bf2f(d.y>>16);
    }
    #pragma unroll
    for (int s5=0;s5<32;s5++){
      float v = ca[s5];
      v += __shfl_xor(v,1); v += __shfl_xor(v,2);
      v += __shfl_xor(v,4); v += __shfl_xor(v,8);
      ca[s5] = v;
    }
    if (ln == 0){
      #pragma unroll
      for (int s5=0;s5<32;s5++){
        int r = (s5>>2)*16 + rg*4 + (s5&3);
        atomicAdd(&cs_out[h*128 + r], ca[s5]);
      }
    }
  }
}

// ---------------- final pass from Q0: cons MFMA + output ----------------
__global__ __launch_bounds__(256) void k_p2(const ushort_t* __restrict__ q0g,
    const float* __restrict__ cs_in, const float* __restrict__ v_fin,
    float* xv_out, const float* __restrict__ alpha, const float* __restrict__ beta){
  __shared__ ushort_t vT[64*128];
  __shared__ float X2[64*68];
  __shared__ float w_lds[128];
  __shared__ float red_lds[256];
  ushort_t* cons_lds = (ushort_t*)X2;
  float* out_lds = X2;

  const int tid = threadIdx.x, lane = tid & 63, wid = tid >> 6;
  const int h = blockIdx.x & 15;
  const int g = blockIdx.x >> 4;
  const int nn = tid & 63, rq = tid >> 6;

  { int r = tid >> 1, dh = (tid & 1)*32;
    #pragma unroll
    for (int i=0;i<32;i++){
      int d = dh + i;
      vT[d*128 + ((r>>3) ^ (d&7))*8 + (r&7)] = f2bf(v_fin[((size_t)r*16 + h)*64 + d]);
    } }
  if (tid < 128) w_lds[tid] = 1.f/(128.f * cs_in[h*128 + tid]);
  __syncthreads();

  const float sa = 1.f/(1.f + __expf(-alpha[h]));
  const float sb = 1.f/(1.f + __expf(-beta[h]));

  for (int t = 0; t < 8; ++t){
    const int i0 = g*512 + t*64;
    const int T  = g*8 + t;
    const ushort_t* ubase = q0g + (size_t)(T*16 + h)*8192;

    float q0v[2][4][4], wreg[2][4][4];
    float up = 0.f;
    #pragma unroll
    for (int m=0;m<2;m++){
      #pragma unroll
      for (int rg=0;rg<4;rg++){
        uint2 d = *(const uint2*)(ubase + (size_t)((rq*2+m)*4 + (nn>>4)))*0 +
                  *(const uint2*)(ubase + ((size_t)((rq*2+m)*4 + (nn>>4)))*256 + (rg*16 + (nn&15))*4);
        float4 w4 = *(const float4*)(w_lds + rq*32 + m*16 + rg*4);
        q0v[m][rg][0] = bf2f(d.x);     wreg[m][rg][0] = w4.x;
        q0v[m][rg][1] = bf2f(d.x>>16); wreg[m][rg][1] = w4.y;
        q0v[m][rg][2] = bf2f(d.y);     wreg[m][rg][2] = w4.z;
        q0v[m][rg][3] = bf2f(d.y>>16); wreg[m][rg][3] = w4.w;
        #pragma unroll
        for (int j=0;j<4;j++) up += q0v[m][rg][j]*wreg[m][rg][j];
      }
    }
    red_lds[rq*64 + nn] = up;
    __syncthreads();   // A
    float u3 = 1.f/(50000.f*(red_lds[nn] + red_lds[64+nn] + red_lds[128+nn] + red_lds[192+nn]));
    float scale = 50000.f * u3;
    #pragma unroll
    for (int m=0;m<2;m++){
      #pragma unroll
      for (int rg=0;rg<4;rg++){
        int r0 = rq*32 + m*16 + rg*4;
        unsigned lo = (unsigned)f2bf(scale*q0v[m][rg][0]*wreg[m][rg][0])
                    | ((unsigned)f2bf(scale*q0v[m][rg][1]*wreg[m][rg][1]) << 16);
        unsigned hi = (unsigned)f2bf(scale*q0v[m][rg][2]*wreg[m][rg][2])
                    | ((unsigned)f2bf(scale*q0v[m][rg][3]*wreg[m][rg][3]) << 16);
        uint2 pv; pv.x = lo; pv.y = hi;
        *(uint2*)(cons_lds + nn*128 + ((r0>>3) ^ (nn&7))*8 + (r0&7)) = pv;
      }
    }
    __syncthreads();   // B: cons ready (also red reads done)
    f32x4 oac[4];
    for (int n=0;n<4;n++) oac[n] = (f32x4){0.f,0.f,0.f,0.f};
    #pragma unroll
    for (int kk=0;kk<4;kk++){
      short8 va = frag128(vT, wid*16 + (lane&15), kk, lane);
      #pragma unroll
      for (int n=0;n<4;n++){
        short8 cf = frag128(cons_lds, n*16 + (lane&15), kk, lane);
        oac[n] = __builtin_amdgcn_mfma_f32_16x16x32_bf16(va, cf, oac[n], 0,0,0);
      }
    }
    __syncthreads();   // C: cons reads done -> reuse region as out_lds
    #pragma unroll
    for (int n=0;n<4;n++) for (int j=0;j<4;j++){
      int d  = wid*16 + (lane>>4)*4 + j;
      int n2 = n*16 + (lane&15);
      out_lds[n2*68 + d] = oac[n][j];
    }
    __syncthreads();   // D
    { int n2 = tid >> 2, d0 = (tid & 3)*16;
      if (i0 + n2 < N_NODES){
        #pragma unroll
        for (int gq=0; gq<4; ++gq){
          float4 vf = *(const float4*)(out_lds + n2*68 + d0 + gq*4);
          float4 xf = *(const float4*)(xv_out + (size_t)(i0+n2)*1024 + h*64 + d0 + gq*4);
          float4 o;
          o.x = sa*xf.x + sb*vf.x;
          o.y = sa*xf.y + sb*vf.y;
          o.z = sa*xf.z + sb*vf.z;
          o.w = sa*xf.w + sb*vf.w;
          *(float4*)(xv_out + (size_t)(i0+n2)*1024 + h*64 + d0 + gq*4) = o;
        }
      } }
    __syncthreads();   // E: out_lds reads done before next tile writes
  }
}

extern "C" void kernel_launch(void* const* d_in, const int* in_sizes, int n_in,
                              void* d_out, int out_size, void* d_ws, size_t ws_size,
                              hipStream_t stream){
  const float* x     = (const float*)d_in[0];
  const float* ni    = (const float*)d_in[1];
  const float* Wq    = (const float*)d_in[2];
  const float* bq    = (const float*)d_in[3];
  const float* keyp  = (const float*)d_in[4];
  const float* Wv    = (const float*)d_in[5];
  const float* bv    = (const float*)d_in[6];
  const float* alpha = (const float*)d_in[7];
  const float* beta  = (const float*)d_in[8];
  const float* Wb    = (const float*)d_in[9];
  const float* bb    = (const float*)d_in[10];
  float* out = (float*)d_out;

  char* ws = (char*)d_ws;
  ushort_t* x_bf   = (ushort_t*)(ws);                     // MPAD*1024 bf16 (dead after gemm)
  float*    v_part = (float*)(ws);                        // NGRP*131072 f32, overlays x_bf
  ushort_t* q_bf   = (ushort_t*)(ws + 102760448);
  ushort_t* w_bf   = (ushort_t*)(ws + 205520896);
  ushort_t* key_bf = (ushort_t*)(ws + 209715200);
  float*    v_fin  = (float*)(ws + 209977344);
  float*    cs     = (float*)(ws + 210501632);
  const size_t Q0_OFF  = 210763776ull;
  const size_t Q0_NEED = Q0_OFF + (size_t)NTILE*16*16384;   // 416284672
  bool bigws = ws_size >= Q0_NEED;
  ushort_t* q0g = bigws ? (ushort_t*)(ws + Q0_OFF) : nullptr;

  (void)hipFuncSetAttribute((const void*)k_gemm,
      hipFuncAttributeMaxDynamicSharedMemorySize, 131072);

  k_zero<<<dim3(24), 256, 0, stream>>>(cs, 6144);
  k_zero<<<dim3(704), 256, 0, stream>>>((float*)(x_bf + (size_t)N_NODES*1024), 90112);
  k_prep_x<<<dim3(25000), 256, 0, stream>>>(x, x_bf);
  k_prep_w<<<dim3(2048*1024/256), 256, 0, stream>>>(Wq, Wv, w_bf);
  k_prep_key<<<dim3(HEAD*KV*HD/256), 256, 0, stream>>>(keyp, key_bf);
  k_gemm<<<dim3(1568), 512, 131072, stream>>>(x_bf, w_bf, bq, bv, q_bf, out);

  dim3 ag(NGRP*16);
  k_attn<0><<<ag, 256, 65024, stream>>>(q_bf, key_bf, ni, Wb, bb, nullptr,  cs,      v_fin, v_part, out, alpha, beta, q0g);
  k_vreduce<<<dim3(512), 256, 0, stream>>>(v_part, v_fin);
  if (bigws){
    k_p1<<<dim3(784), 256, 0, stream>>>(q0g, cs,       cs+2048);
    k_p1<<<dim3(784), 256, 0, stream>>>(q0g, cs+2048,  cs+4096);
    k_p2<<<dim3(NGRP*16), 256, 0, stream>>>(q0g, cs+4096, v_fin, out, alpha, beta);
  } else {
    k_attn<1><<<ag, 256, 40448, stream>>>(q_bf, key_bf, ni, Wb, bb, cs,       cs+2048, v_fin, v_part, out, alpha, beta, nullptr);
    k_attn<1><<<ag, 256, 40448, stream>>>(q_bf, key_bf, ni, Wb, bb, cs+2048,  cs+4096, v_fin, v_part, out, alpha, beta, nullptr);
    k_attn<2><<<ag, 256, 65024, stream>>>(q_bf, key_bf, ni, Wb, bb, cs+4096,  nullptr, v_fin, v_part, out, alpha, beta, nullptr);
  }
}

// Round 8
// 921.537 us; speedup vs baseline: 1.2316x; 1.2316x over previous
//
#include <hip/hip_runtime.h>

#define N_NODES 50000
#define MPAD    50176   // 196*256 = 98*512 = 3136*16
#define DIM     1024
#define HEAD    16
#define KV      128
#define HD      64
#define NGRP    98      // MPAD/512

typedef unsigned short ushort_t;
typedef short short8 __attribute__((ext_vector_type(8)));
typedef float f32x4 __attribute__((ext_vector_type(4)));

__device__ inline unsigned short f2bf(float f){
  union { float f; unsigned u; } v; v.f = f;
  unsigned u = v.u;
  unsigned r = (u + 0x7FFFu + ((u >> 16) & 1u)) >> 16;
  return (unsigned short)r;
}
__device__ inline float bf2f(unsigned u16){
  union { unsigned u; float f; } v; v.u = (u16 & 0xFFFFu) << 16; return v.f;
}

__device__ inline void gload_lds16(const void* g, void* l){
  __builtin_amdgcn_global_load_lds(
      (const __attribute__((address_space(1))) void*)g,
      (__attribute__((address_space(3))) void*)l, 16, 0, 0);
}

// [*][64] / [*][128] bf16 LDS tiles, 16B-chunk XOR-swizzled by (row&7)
__device__ inline short8 frag64(const ushort_t* lds, int row, int kk, int lane){
  int c  = kk*4 + (lane >> 4);
  int cc = c ^ (row & 7);
  return *(const short8*)(lds + row*64 + cc*8);
}
__device__ inline short8 frag128(const ushort_t* lds, int row, int kk, int lane){
  int c  = kk*4 + (lane >> 4);
  int cc = c ^ (row & 7);
  return *(const short8*)(lds + row*128 + cc*8);
}

// ---------------- prep kernels ----------------
__global__ void k_zero(float* p, int n){
  int i = blockIdx.x*256 + threadIdx.x;
  if (i < n) p[i] = 0.f;
}

// x fp32 -> bf16, 16B-chunk swizzle keyed by row&7 (r4 layout for frag64 GEMM)
__global__ void k_prep_x(const float* __restrict__ x, ushort_t* __restrict__ x_bf){
  int idx = blockIdx.x*256 + threadIdx.x;
  int row = idx >> 7, c = idx & 127;
  const float4* s = (const float4*)(x + (size_t)row*1024 + c*8);
  float4 f0 = s[0], f1 = s[1];
  short8 v;
  v[0]=(short)f2bf(f0.x); v[1]=(short)f2bf(f0.y); v[2]=(short)f2bf(f0.z); v[3]=(short)f2bf(f0.w);
  v[4]=(short)f2bf(f1.x); v[5]=(short)f2bf(f1.y); v[6]=(short)f2bf(f1.z); v[7]=(short)f2bf(f1.w);
  int sc = (c & ~7) | ((c ^ row) & 7);
  *(short8*)(x_bf + (size_t)row*1024 + sc*8) = v;
}

// W concat (rows 0..1023 = Wq, 1024..2047 = Wv), bf16, row&7-keyed chunk swizzle
__global__ void k_prep_w(const float* __restrict__ Wq, const float* __restrict__ Wv,
                         ushort_t* __restrict__ w_bf){
  int idx = blockIdx.x*256 + threadIdx.x;
  int j = idx >> 10, k = idx & 1023;
  float v = (j < 1024) ? Wq[idx] : Wv[(size_t)(j-1024)*1024 + k];
  int d = k & 63;
  int scol = (k & ~63) | ((((d>>3) ^ (j & 7)) & 7) << 3) | (d & 7);
  w_bf[(size_t)j*1024 + scol] = f2bf(v);
}

// key_bf[h][r][swz(d, r)]  from key_p[r][h][d]
__global__ void k_prep_key(const float* __restrict__ key_p, ushort_t* __restrict__ key_bf){
  int idx = blockIdx.x*256 + threadIdx.x;
  int h = idx >> 13, rem = idx & 8191;
  int r = rem >> 6, d = rem & 63;
  float v = key_p[(size_t)(r*HEAD + h)*HD + d];
  int pos = ((((d>>3) ^ (r & 7)) & 7) << 3) | (d & 7);
  key_bf[(size_t)h*8192 + r*64 + pos] = f2bf(v);
}

// sum the NGRP v-slices
__global__ void k_vreduce(const float* __restrict__ vp, float* __restrict__ vout){
  int i = blockIdx.x*256 + threadIdx.x;
  float s = 0.f;
  for (int gg = 0; gg < NGRP; ++gg) s += vp[(size_t)gg*131072 + i];
  vout[i] = s;
}

// ---------------- big GEMM: [q|xv] = x @ [Wq;Wv]^T + [bq;bv] ----------------
// r4 loop (256x256, BK=64, dist-2 prefetch, counted vmcnt(8)) + LDS-image epilogue.
__global__ __launch_bounds__(512) void k_gemm(const ushort_t* __restrict__ x_bf,
    const ushort_t* __restrict__ w_bf, const float* __restrict__ bq,
    const float* __restrict__ bv, ushort_t* __restrict__ q_bf, float* xv_out){
  extern __shared__ char gsm[];
  ushort_t* As = (ushort_t*)gsm;            // 2 x 32KB
  ushort_t* Bs = (ushort_t*)(gsm + 65536);  // 2 x 32KB
  const int tid = threadIdx.x, lane = tid & 63;
  const int wid = tid >> 6, wr = wid >> 2, wc = wid & 3;
  int b = blockIdx.x;
  int wg = (b & 7)*196 + (b >> 3);          // bijective XCD swizzle (1568 = 8*196)
  const int bm0 = (wg >> 3) * 256, bn0 = (wg & 7) * 256;

  f32x4 acc[8][4];
  #pragma unroll
  for (int m=0;m<8;m++)
    #pragma unroll
    for (int n=0;n<4;n++) acc[m][n] = (f32x4){0.f,0.f,0.f,0.f};

  const ushort_t* asrc = x_bf + (size_t)bm0*1024;
  const ushort_t* bsrc = w_bf + (size_t)bn0*1024;

#define STAGE(kt, bi)                                                    \
  { _Pragma("unroll")                                                    \
    for (int it=0; it<4; ++it){                                          \
      int chunk = it*512 + tid;                                          \
      int r = chunk >> 3, c = chunk & 7;                                 \
      gload_lds16(asrc + (size_t)r*1024 + (kt)*64 + c*8,                 \
                  As + (bi)*16384 + chunk*8);                            \
    }                                                                    \
    _Pragma("unroll")                                                    \
    for (int it=0; it<4; ++it){                                          \
      int chunk = it*512 + tid;                                          \
      int r = chunk >> 3, c = chunk & 7;                                 \
      gload_lds16(bsrc + (size_t)r*1024 + (kt)*64 + c*8,                 \
                  Bs + (bi)*16384 + chunk*8);                            \
    }                                                                    \
  }

  STAGE(0, 0);
  STAGE(1, 1);

  for (int kt = 0; kt < 16; ++kt){
    const int cur = kt & 1;
    if (kt == 15) { asm volatile("s_waitcnt vmcnt(0)" ::: "memory"); }
    else          { asm volatile("s_waitcnt vmcnt(8)" ::: "memory"); }
    __builtin_amdgcn_s_barrier();

    const ushort_t* ab  = As + cur*16384;
    const ushort_t* bb_ = Bs + cur*16384;
    #pragma unroll
    for (int kk=0;kk<2;kk++){
      short8 bfr[4];
      #pragma unroll
      for (int n=0;n<4;n++) bfr[n] = frag64(bb_, wc*64 + n*16 + (lane&15), kk, lane);
      #pragma unroll
      for (int m=0;m<8;m++){
        short8 af = frag64(ab, wr*128 + m*16 + (lane&15), kk, lane);
        #pragma unroll
        for (int n=0;n<4;n++)
          acc[m][n] = __builtin_amdgcn_mfma_f32_16x16x32_bf16(af, bfr[n], acc[m][n], 0,0,0);
      }
    }
    __builtin_amdgcn_s_barrier();
    if (kt + 2 < 16) STAGE(kt+2, cur);
  }
#undef STAGE

  __syncthreads();   // drain; LDS free for epilogue staging

  const bool isq = bn0 < 1024;
  float biasv[4];
  #pragma unroll
  for (int n=0;n<4;n++){
    int col = bn0 + wc*64 + n*16 + (lane & 15);
    biasv[n] = isq ? bq[col] : bv[col - 1024];
  }

  if (isq){
    // stage bf16 image (attn swizzle applied here), then full-line copies out
    ushort_t* img = (ushort_t*)gsm;   // 256 x 256 bf16 = 128KB
    #pragma unroll
    for (int n=0;n<4;n++){
      int lcol = wc*64 + n*16 + (lane & 15);
      int d = lcol & 63;
      #pragma unroll
      for (int m=0;m<8;m++){
        #pragma unroll
        for (int j=0;j<4;j++){
          int lrow = wr*128 + m*16 + (lane>>4)*4 + j;
          int sc = (lcol & ~63) | ((((d>>3) ^ (lrow & 7)) & 7) << 3) | (d & 7);
          img[lrow*256 + sc] = f2bf(acc[m][n][j] + biasv[n]);
        }
      }
    }
    __syncthreads();
    #pragma unroll
    for (int it=0; it<16; ++it){
      int r  = it*16 + (tid >> 5);
      int ch = tid & 31;
      short8 v = *(const short8*)(img + r*256 + ch*8);
      *(short8*)(q_bf + (size_t)(bm0 + r)*1024 + bn0 + ch*8) = v;
    }
  } else {
    #pragma unroll
    for (int n=0;n<4;n++){
      int col = bn0 + wc*64 + n*16 + (lane & 15);
      #pragma unroll
      for (int m=0;m<8;m++){
        #pragma unroll
        for (int j=0;j<4;j++){
          int row = bm0 + wr*128 + m*16 + (lane>>4)*4 + j;
          if (row < N_NODES)
            xv_out[(size_t)row*1024 + (col - 1024)] = acc[m][n][j] + biasv[n];
        }
      }
    }
  }
}

// ---------------- wave-autonomous sinkhorn pass (replaces k_attn<1>) ----------------
// Swapped QK: D = attn[node, r]; all reductions wave-local; key+Wb+w held in regs.
// cs_out[h,r] += sum_n u(n)*Q0(n,r);  u = 1/(50000*sum_r Q0*w);  w = 1/(128*cs_in).
__global__ __launch_bounds__(256) void k_s1(const ushort_t* __restrict__ q_bf,
    const ushort_t* __restrict__ key_bf, const float* __restrict__ ni,
    const float* __restrict__ Wb, const float* __restrict__ bb,
    const float* __restrict__ cs_in, float* __restrict__ cs_out){
  __shared__ float col_acc[4][128];
  const int tid = threadIdx.x, lane = tid & 63, wid = tid >> 6;
  const int h   = blockIdx.x & 15;
  const int blk = blockIdx.x >> 4;          // 0..97
  const int gw  = blk*4 + wid;              // 0..391 wave index within head
  const int cl  = lane & 15, rg = lane >> 4;

  // per-lane slot set r_n = n*16 + cl  (fixed across units)
  float wbv[8][4], bbr[8], wv[8];
  #pragma unroll
  for (int n=0;n<8;n++){
    int r = h*128 + n*16 + cl;
    float4 w4 = *(const float4*)(Wb + (size_t)r*4);
    wbv[n][0]=w4.x; wbv[n][1]=w4.y; wbv[n][2]=w4.z; wbv[n][3]=w4.w;
    bbr[n] = bb[r];
    wv[n]  = 1.f/(128.f*cs_in[r]);
  }
  // key B-frags held in regs (64 VGPR)
  short8 kf[8][2];
  #pragma unroll
  for (int n=0;n<8;n++)
    #pragma unroll
    for (int kk=0;kk<2;kk++){
      int c = (kk*4+rg) ^ (cl & 7);
      kf[n][kk] = *(const short8*)(key_bf + (size_t)h*8192 + (n*16+cl)*64 + c*8);
    }

  float cs_acc[8];
  #pragma unroll
  for (int n=0;n<8;n++) cs_acc[n] = 0.f;

  const int g0 = gw*8;      // 8 units of 16 nodes each
  short8 qc[2], qn[2];
  { int row = g0*16 + cl;
    #pragma unroll
    for (int kk=0;kk<2;kk++){
      int c = (kk*4+rg) ^ (row & 7);
      qc[kk] = *(const short8*)(q_bf + (size_t)row*1024 + h*64 + c*8);
    } }

  for (int u = 0; u < 8; ++u){
    const int i0 = (g0+u)*16;
    if (u+1 < 8){
      int row = i0 + 16 + cl;
      #pragma unroll
      for (int kk=0;kk<2;kk++){
        int c = (kk*4+rg) ^ (row & 7);
        qn[kk] = *(const short8*)(q_bf + (size_t)row*1024 + h*64 + c*8);
      }
    }
    float4 ni4[4];
    #pragma unroll
    for (int j=0;j<4;j++){
      int row = i0 + rg*4 + j;
      if (row < N_NODES) ni4[j] = *(const float4*)(ni + (size_t)row*4);
      else { ni4[j].x=0.f; ni4[j].y=0.f; ni4[j].z=0.f; ni4[j].w=0.f; }
    }
    f32x4 acc[8];
    #pragma unroll
    for (int n=0;n<8;n++) acc[n] = (f32x4){0.f,0.f,0.f,0.f};
    #pragma unroll
    for (int n=0;n<8;n++){
      acc[n] = __builtin_amdgcn_mfma_f32_16x16x32_bf16(qc[0], kf[n][0], acc[n], 0,0,0);
      acc[n] = __builtin_amdgcn_mfma_f32_16x16x32_bf16(qc[1], kf[n][1], acc[n], 0,0,0);
    }
    float a[8][4];
    #pragma unroll
    for (int n=0;n<8;n++)
      #pragma unroll
      for (int j=0;j<4;j++)
        a[n][j] = acc[n][j]*0.125f
                + wbv[n][0]*ni4[j].x + wbv[n][1]*ni4[j].y
                + wbv[n][2]*ni4[j].z + wbv[n][3]*ni4[j].w + bbr[n];

    float mj[4], sj[4];
    #pragma unroll
    for (int j=0;j<4;j++){
      float m0 = a[0][j];
      #pragma unroll
      for (int n=1;n<8;n++) m0 = fmaxf(m0, a[n][j]);
      m0 = fmaxf(m0, __shfl_xor(m0,1));
      m0 = fmaxf(m0, __shfl_xor(m0,2));
      m0 = fmaxf(m0, __shfl_xor(m0,4));
      m0 = fmaxf(m0, __shfl_xor(m0,8));
      mj[j] = m0;
    }
    #pragma unroll
    for (int j=0;j<4;j++){
      float s = 0.f;
      #pragma unroll
      for (int n=0;n<8;n++){ float e = __expf(a[n][j]-mj[j]); a[n][j]=e; s+=e; }
      s += __shfl_xor(s,1); s += __shfl_xor(s,2);
      s += __shfl_xor(s,4); s += __shfl_xor(s,8);
      sj[j] = s;
    }
    #pragma unroll
    for (int j=0;j<4;j++){
      float inv = 20.f/sj[j];
      #pragma unroll
      for (int n=0;n<8;n++) a[n][j] = __expf(a[n][j]*inv);
    }
    float uj[4];
    #pragma unroll
    for (int j=0;j<4;j++){
      float s = 0.f;
      #pragma unroll
      for (int n=0;n<8;n++) s += a[n][j]*wv[n];
      s += __shfl_xor(s,1); s += __shfl_xor(s,2);
      s += __shfl_xor(s,4); s += __shfl_xor(s,8);
      int row = i0 + rg*4 + j;
      uj[j] = (row < N_NODES) ? 1.f/(50000.f*s) : 0.f;
    }
    #pragma unroll
    for (int n=0;n<8;n++)
      cs_acc[n] += a[n][0]*uj[0] + a[n][1]*uj[1] + a[n][2]*uj[2] + a[n][3]*uj[3];

    qc[0] = qn[0]; qc[1] = qn[1];
  }

  #pragma unroll
  for (int n=0;n<8;n++){
    float v = cs_acc[n];
    v += __shfl_xor(v,16); v += __shfl_xor(v,32);
    cs_acc[n] = v;
  }
  if (rg == 0){
    #pragma unroll
    for (int n=0;n<8;n++) col_acc[wid][n*16+cl] = cs_acc[n];
  }
  __syncthreads();
  if (tid < 128)
    atomicAdd(&cs_out[h*128+tid],
      col_acc[0][tid]+col_acc[1][tid]+col_acc[2][tid]+col_acc[3][tid]);
}

// ---------------- attn passes P0 / P2 (r6 structure, looped 8 tiles) ----------------
template<int PHASE>
__global__ __launch_bounds__(256) void k_attn(
    const ushort_t* __restrict__ q_bf, const ushort_t* __restrict__ key_bf,
    const float* __restrict__ node_index, const float* __restrict__ Wb,
    const float* __restrict__ bb, const float* __restrict__ colsum_in,
    float* __restrict__ colsum_out, const float* __restrict__ v_fin,
    float* __restrict__ v_part, float* xv_out,
    const float* __restrict__ alpha, const float* __restrict__ beta)
{
  constexpr int QB    = (PHASE == 2) ? 1 : 2;
  constexpr int O_Q   = 0;
  constexpr int O_KEY = O_Q + QB*8192;
  constexpr int O_NI  = O_KEY + 16384;
  constexpr int O_WB  = O_NI + QB*1024;
  constexpr int O_RED = O_WB + 2560;
  constexpr int O_COL = O_RED + 2048;
  constexpr int O_W   = O_COL + 512;
  constexpr int O_X1  = O_W + 512;
  constexpr int O_X2  = O_X1 + 16384;

  extern __shared__ char smem[];
  ushort_t* q_lds   = (ushort_t*)(smem + O_Q);
  ushort_t* key_lds = (ushort_t*)(smem + O_KEY);
  float* ni_lds  = (float*)(smem + O_NI);
  float* wb_lds  = (float*)(smem + O_WB);
  float* red_lds = (float*)(smem + O_RED);
  float* col_acc = (float*)(smem + O_COL);
  float* w_lds   = (float*)(smem + O_W);
  ushort_t* sigT     = (ushort_t*)(smem + O_X1);
  ushort_t* xvT      = (ushort_t*)(smem + O_X2);
  ushort_t* vT       = (ushort_t*)(smem + O_X1);
  ushort_t* cons_lds = (ushort_t*)(smem + O_X2);
  float*    out_lds  = (float*)(smem + O_X2);

  const int tid = threadIdx.x, lane = tid & 63, wid = tid >> 6;
  const int h    = blockIdx.x & 15;
  const int g    = blockIdx.x >> 4;
  const int base = g * 512;
  int NT = (MPAD - base) >> 6; if (NT > 8) NT = 8;

  #pragma unroll
  for (int it = 0; it < 4; ++it){
    int chunk = it*256 + tid;
    gload_lds16(key_bf + (size_t)h*8192 + chunk*8, key_lds + chunk*8);
  }
  #pragma unroll
  for (int it = 0; it < 2; ++it){
    int chunk = it*256 + tid;
    int r = chunk >> 3, c = chunk & 7;
    gload_lds16(q_bf + (size_t)(base + r)*1024 + h*64 + c*8, q_lds + chunk*8);
  }
  { int r = tid >> 2, c = tid & 3;
    ni_lds[tid] = (base + r < N_NODES) ? node_index[(size_t)(base + r)*4 + c] : 0.f; }
  if (tid < 128){
    #pragma unroll
    for (int c=0;c<4;c++) wb_lds[tid*5+c] = Wb[(size_t)(h*128 + tid)*4 + c];
    wb_lds[tid*5+4] = bb[h*128 + tid];
    if (PHASE >= 1) w_lds[tid] = 1.f / (128.f * colsum_in[h*128 + tid]);
    if (PHASE <= 1) col_acc[tid] = 0.f;
  }
  if constexpr (PHASE == 2){
    int r = tid >> 1, dh = (tid & 1)*32;
    #pragma unroll
    for (int i=0;i<32;i++){
      int d = dh + i;
      vT[d*128 + ((r>>3) ^ (d&7))*8 + (r&7)] = f2bf(v_fin[((size_t)r*16 + h)*64 + d]);
    }
  }
  float xvr[16], xvn[16];
  if constexpr (PHASE == 0){
    int d = tid & 63, q4 = tid >> 6;
    #pragma unroll
    for (int i=0;i<16;i++){
      int row = base + q4*16 + i;
      xvr[i] = (row < N_NODES) ? xv_out[(size_t)row*1024 + h*64 + d] : 0.f;
    }
  }
  f32x4 vac[2][4];
  if constexpr (PHASE == 0)
    for (int m=0;m<2;m++) for (int n=0;n<4;n++) vac[m][n] = (f32x4){0.f,0.f,0.f,0.f};

  __syncthreads();

  for (int t = 0; t < NT; ++t){
    const int i0  = base + t*64;
    const int cur = t & 1;
    const ushort_t* qb  = q_lds  + ((QB==2) ? cur*4096 : 0);
    const float*    nib = ni_lds + ((QB==2) ? cur*256  : 0);
    float ni_next = 0.f;

    if constexpr (QB == 2){
      if (t+1 < NT){
        int i1 = i0 + 64;
        #pragma unroll
        for (int it = 0; it < 2; ++it){
          int chunk = it*256 + tid;
          int r = chunk >> 3, c = chunk & 7;
          gload_lds16(q_bf + (size_t)(i1 + r)*1024 + h*64 + c*8,
                      q_lds + (cur^1)*4096 + chunk*8);
        }
        int r = tid >> 2, c = tid & 3;
        ni_next = (i0 + 64 + r < N_NODES) ? node_index[(size_t)(i0+64+r)*4 + c] : 0.f;
      }
    } else {
      if (t+1 < NT){
        int r = tid >> 2, c = tid & 3;
        ni_next = (i0 + 64 + r < N_NODES) ? node_index[(size_t)(i0+64+r)*4 + c] : 0.f;
      }
    }
    if constexpr (PHASE == 0){
      if (t+1 < NT){
        int d = tid & 63, q4 = tid >> 6;
        #pragma unroll
        for (int i=0;i<16;i++){
          int row = i0 + 64 + q4*16 + i;
          xvn[i] = (row < N_NODES) ? xv_out[(size_t)row*1024 + h*64 + d] : 0.f;
        }
      }
    }

    f32x4 acc[2][4];
    for (int m=0;m<2;m++) for (int n=0;n<4;n++) acc[m][n] = (f32x4){0.f,0.f,0.f,0.f};
    #pragma unroll
    for (int kk = 0; kk < 2; ++kk){
      short8 kf[2];
      #pragma unroll
      for (int m=0;m<2;m++) kf[m] = frag64(key_lds, wid*32 + m*16 + (lane&15), kk, lane);
      #pragma unroll
      for (int n=0;n<4;n++){
        short8 qf = frag64(qb, n*16 + (lane&15), kk, lane);
        #pragma unroll
        for (int m=0;m<2;m++)
          acc[m][n] = __builtin_amdgcn_mfma_f32_16x16x32_bf16(kf[m], qf, acc[m][n], 0,0,0);
      }
    }

    float nif[4][4];
    #pragma unroll
    for (int n=0;n<4;n++){
      int nn = n*16 + (lane&15);
      #pragma unroll
      for (int c=0;c<4;c++) nif[n][c] = nib[nn*4+c];
    }
    float a[2][4][4];
    #pragma unroll
    for (int m=0;m<2;m++){
      #pragma unroll
      for (int j=0;j<4;j++){
        int r = wid*32 + m*16 + (lane>>4)*4 + j;
        float w0 = wb_lds[r*5+0], w1 = wb_lds[r*5+1];
        float w2 = wb_lds[r*5+2], w3 = wb_lds[r*5+3], w4 = wb_lds[r*5+4];
        #pragma unroll
        for (int n=0;n<4;n++){
          float b = w4 + w0*nif[n][0] + w1*nif[n][1] + w2*nif[n][2] + w3*nif[n][3];
          a[m][n][j] = acc[m][n][j]*0.125f + b;
        }
      }
    }

    float vmask[4];
    #pragma unroll
    for (int n=0;n<4;n++) vmask[n] = (i0 + n*16 + (lane&15) < N_NODES) ? 1.f : 0.f;

    if constexpr (PHASE == 0){
      #pragma unroll
      for (int m=0;m<2;m++) for (int n=0;n<4;n++) for (int j=0;j<4;j++){
        int r  = wid*32 + m*16 + (lane>>4)*4 + j;
        int nn = n*16 + (lane&15);
        float sg = vmask[n] / (1.f + __expf(-a[m][n][j]));
        sigT[r*64 + ((((nn>>3) ^ (r&7)) & 7) << 3) + (nn&7)] = f2bf(sg);
      }
      { int d = tid & 63, q4 = tid >> 6;
        #pragma unroll
        for (int i=0;i<16;i++){
          int nn = q4*16 + i;
          xvT[d*64 + ((((nn>>3) ^ (d&7)) & 7) << 3) + (nn&7)] = f2bf(xvr[i]);
        }
      }
    }

    float pm[4];
    #pragma unroll
    for (int n=0;n<4;n++){
      float m0 = a[0][n][0];
      #pragma unroll
      for (int m=0;m<2;m++) for (int j=0;j<4;j++) m0 = fmaxf(m0, a[m][n][j]);
      m0 = fmaxf(m0, __shfl_xor(m0, 16));
      m0 = fmaxf(m0, __shfl_xor(m0, 32));
      pm[n] = m0;
    }
    if (lane < 16){
      #pragma unroll
      for (int n=0;n<4;n++) red_lds[wid*64 + n*16 + lane] = pm[n];
    }
    __syncthreads();

    if constexpr (QB == 1){
      if (t+1 < NT){
        int i1 = i0 + 64;
        #pragma unroll
        for (int it = 0; it < 2; ++it){
          int chunk = it*256 + tid;
          int r = chunk >> 3, c = chunk & 7;
          gload_lds16(q_bf + (size_t)(i1 + r)*1024 + h*64 + c*8, q_lds + chunk*8);
        }
        ni_lds[tid] = ni_next;
      }
    }

    float mnn[4], snn[4];
    #pragma unroll
    for (int n=0;n<4;n++){
      int nn = n*16 + (lane&15);
      float m0 = red_lds[nn];
      m0 = fmaxf(m0, red_lds[64+nn]); m0 = fmaxf(m0, red_lds[128+nn]); m0 = fmaxf(m0, red_lds[192+nn]);
      mnn[n] = m0;
    }
    #pragma unroll
    for (int n=0;n<4;n++){
      float s = 0.f;
      #pragma unroll
      for (int m=0;m<2;m++) for (int j=0;j<4;j++){
        float e = __expf(a[m][n][j] - mnn[n]);
        a[m][n][j] = e; s += e;
      }
      s += __shfl_xor(s, 16); s += __shfl_xor(s, 32);
      snn[n] = s;
    }
    if (lane < 16){
      #pragma unroll
      for (int n=0;n<4;n++) red_lds[256 + wid*64 + n*16 + lane] = snn[n];
    }

    if constexpr (PHASE == 0){
      #pragma unroll
      for (int kk=0;kk<2;kk++){
        short8 sa[2];
        #pragma unroll
        for (int m=0;m<2;m++) sa[m] = frag64(sigT, wid*32 + m*16 + (lane&15), kk, lane);
        #pragma unroll
        for (int n=0;n<4;n++){
          short8 xf = frag64(xvT, n*16 + (lane&15), kk, lane);
          #pragma unroll
          for (int m=0;m<2;m++)
            vac[m][n] = __builtin_amdgcn_mfma_f32_16x16x32_bf16(sa[m], xf, vac[m][n], 0,0,0);
        }
      }
    }
    __syncthreads();

    #pragma unroll
    for (int n=0;n<4;n++){
      int nn = n*16 + (lane&15);
      snn[n] = red_lds[256+nn] + red_lds[256+64+nn] + red_lds[256+128+nn] + red_lds[256+192+nn];
    }
    #pragma unroll
    for (int n=0;n<4;n++){
      float inv = 20.f / snn[n];
      #pragma unroll
      for (int m=0;m<2;m++) for (int j=0;j<4;j++)
        a[m][n][j] = __expf(a[m][n][j] * inv);
    }

    float uval[4];
    if constexpr (PHASE >= 1){
      #pragma unroll
      for (int n=0;n<4;n++){
        float s = 0.f;
        #pragma unroll
        for (int m=0;m<2;m++){
          #pragma unroll
          for (int j=0;j<4;j++){
            int r = wid*32 + m*16 + (lane>>4)*4 + j;
            s += a[m][n][j] * w_lds[r];
          }
        }
        s += __shfl_xor(s, 16); s += __shfl_xor(s, 32);
        uval[n] = s;
      }
      if (lane < 16){
        #pragma unroll
        for (int n=0;n<4;n++) red_lds[wid*64 + n*16 + lane] = uval[n];
      }
      __syncthreads();
      #pragma unroll
      for (int n=0;n<4;n++){
        int nn = n*16 + (lane&15);
        float s = red_lds[nn] + red_lds[64+nn] + red_lds[128+nn] + red_lds[192+nn];
        uval[n] = 1.f / (50000.f * s);
      }
    }

    if constexpr (PHASE <= 1){
      float cs[2][4];
      #pragma unroll
      for (int m=0;m<2;m++){
        #pragma unroll
        for (int j=0;j<4;j++){
          float s = 0.f;
          #pragma unroll
          for (int n=0;n<4;n++){
            float tv = a[m][n][j] * vmask[n];
            if (PHASE == 1) tv *= uval[n];
            s += tv;
          }
          s += __shfl_xor(s, 1); s += __shfl_xor(s, 2);
          s += __shfl_xor(s, 4); s += __shfl_xor(s, 8);
          cs[m][j] = s;
        }
      }
      if ((lane & 15) == 0){
        #pragma unroll
        for (int m=0;m<2;m++) for (int j=0;j<4;j++){
          int r = wid*32 + m*16 + (lane>>4)*4 + j;
          col_acc[r] += cs[m][j];
        }
      }
    }

    if constexpr (PHASE == 2){
      #pragma unroll
      for (int m=0;m<2;m++) for (int n=0;n<4;n++) for (int j=0;j<4;j++){
        int r  = wid*32 + m*16 + (lane>>4)*4 + j;
        int nn = n*16 + (lane&15);
        float cv = 50000.f * uval[n] * a[m][n][j] * w_lds[r];
        cons_lds[nn*128 + ((r>>3) ^ (nn&7))*8 + (r&7)] = f2bf(cv);
      }
      __syncthreads();
      f32x4 oac[4];
      for (int n=0;n<4;n++) oac[n] = (f32x4){0.f,0.f,0.f,0.f};
      #pragma unroll
      for (int kk=0;kk<4;kk++){
        short8 va = frag128(vT, wid*16 + (lane&15), kk, lane);
        #pragma unroll
        for (int n=0;n<4;n++){
          short8 cf = frag128(cons_lds, n*16 + (lane&15), kk, lane);
          oac[n] = __builtin_amdgcn_mfma_f32_16x16x32_bf16(va, cf, oac[n], 0,0,0);
        }
      }
      __syncthreads();
      #pragma unroll
      for (int n=0;n<4;n++) for (int j=0;j<4;j++){
        int d  = wid*16 + (lane>>4)*4 + j;
        int nn = n*16 + (lane&15);
        out_lds[nn*68 + d] = oac[n][j];
      }
      __syncthreads();
      float sa = 1.f/(1.f + __expf(-alpha[h]));
      float sb = 1.f/(1.f + __expf(-beta[h]));
      int nn = tid >> 2, d0 = (tid & 3)*16;
      if (i0 + nn < N_NODES){
        #pragma unroll
        for (int gq=0; gq<4; ++gq){
          float4 vf = *(const float4*)(out_lds + nn*68 + d0 + gq*4);
          float4 xf = *(const float4*)(xv_out + (size_t)(i0+nn)*1024 + h*64 + d0 + gq*4);
          float4 o;
          o.x = sa*xf.x + sb*vf.x;
          o.y = sa*xf.y + sb*vf.y;
          o.z = sa*xf.z + sb*vf.z;
          o.w = sa*xf.w + sb*vf.w;
          *(float4*)(xv_out + (size_t)(i0+nn)*1024 + h*64 + d0 + gq*4) = o;
        }
      }
    } else {
      if (t+1 < NT && QB == 2) ni_lds[(cur^1)*256 + tid] = ni_next;
      if constexpr (PHASE == 0){
        if (t+1 < NT){
          #pragma unroll
          for (int i=0;i<16;i++) xvr[i] = xvn[i];
        }
      }
      __syncthreads();
    }
  }

  if constexpr (PHASE == 0){
    float* vdst = v_part + (size_t)g*131072;
    #pragma unroll
    for (int m=0;m<2;m++) for (int n=0;n<4;n++) for (int j=0;j<4;j++){
      int r = wid*32 + m*16 + (lane>>4)*4 + j;
      int d = n*16 + (lane&15);
      vdst[((size_t)r*16 + h)*64 + d] = vac[m][n][j];
    }
  }
  if constexpr (PHASE <= 1){
    if (tid < 128) atomicAdd(&colsum_out[h*128 + tid], col_acc[tid]);
  }
}

extern "C" void kernel_launch(void* const* d_in, const int* in_sizes, int n_in,
                              void* d_out, int out_size, void* d_ws, size_t ws_size,
                              hipStream_t stream){
  const float* x     = (const float*)d_in[0];
  const float* ni    = (const float*)d_in[1];
  const float* Wq    = (const float*)d_in[2];
  const float* bq    = (const float*)d_in[3];
  const float* keyp  = (const float*)d_in[4];
  const float* Wv    = (const float*)d_in[5];
  const float* bv    = (const float*)d_in[6];
  const float* alpha = (const float*)d_in[7];
  const float* beta  = (const float*)d_in[8];
  const float* Wb    = (const float*)d_in[9];
  const float* bb    = (const float*)d_in[10];
  float* out = (float*)d_out;

  char* ws = (char*)d_ws;
  ushort_t* x_bf   = (ushort_t*)(ws);                     // MPAD*1024 bf16 (dead after gemm)
  float*    v_part = (float*)(ws);                        // NGRP*131072 f32, overlays x_bf
  ushort_t* q_bf   = (ushort_t*)(ws + 102760448);
  ushort_t* w_bf   = (ushort_t*)(ws + 205520896);
  ushort_t* key_bf = (ushort_t*)(ws + 209715200);
  float*    v_fin  = (float*)(ws + 209977344);
  float*    cs     = (float*)(ws + 210501632);

  (void)hipFuncSetAttribute((const void*)k_gemm,
      hipFuncAttributeMaxDynamicSharedMemorySize, 131072);

  k_zero<<<dim3(24), 256, 0, stream>>>(cs, 6144);
  k_zero<<<dim3(704), 256, 0, stream>>>((float*)(x_bf + (size_t)N_NODES*1024), 90112);
  k_prep_x<<<dim3(25000), 256, 0, stream>>>(x, x_bf);
  k_prep_w<<<dim3(2048*1024/256), 256, 0, stream>>>(Wq, Wv, w_bf);
  k_prep_key<<<dim3(HEAD*KV*HD/256), 256, 0, stream>>>(keyp, key_bf);
  k_gemm<<<dim3(1568), 512, 131072, stream>>>(x_bf, w_bf, bq, bv, q_bf, out);

  dim3 ag(NGRP*16);
  k_attn<0><<<ag, 256, 65024, stream>>>(q_bf, key_bf, ni, Wb, bb, nullptr,  cs,      v_fin, v_part, out, alpha, beta);
  k_vreduce<<<dim3(512), 256, 0, stream>>>(v_part, v_fin);
  k_s1<<<dim3(1568), 256, 0, stream>>>(q_bf, key_bf, ni, Wb, bb, cs,      cs+2048);
  k_s1<<<dim3(1568), 256, 0, stream>>>(q_bf, key_bf, ni, Wb, bb, cs+2048, cs+4096);
  k_attn<2><<<ag, 256, 65024, stream>>>(q_bf, key_bf, ni, Wb, bb, cs+4096, nullptr, v_fin, v_part, out, alpha, beta);
}